// Round 5
// baseline (298.571 us; speedup 1.0000x reference)
//
#include <hip/hip_runtime.h>
#include <math.h>

#define BB 4
#define SS 512
#define PP 128
#define CC 64
#define KK 64
#define NCTX_ 16
#define TT 64
#define NTILES ((BB*SS)/TT)   // 32

typedef __attribute__((ext_vector_type(8))) short bf16x8;
typedef __attribute__((ext_vector_type(4))) float f32x4;

static __device__ __forceinline__ float bf2f(short h) {
    unsigned u = ((unsigned)(unsigned short)h) << 16;
    return __builtin_bit_cast(float, u);
}
static __device__ __forceinline__ short f2bf(float f) {
    unsigned u = __builtin_bit_cast(unsigned, f);
    unsigned r = (u + 0x7fffu + ((u >> 16) & 1u)) >> 16;
    return (short)(unsigned short)r;
}

// ---------------------------------------------------------------------------
// Repack W1 (c,k,ctx,p) -> (c,k,p4,ctx) as float4 (Phase B gather locality).
// ---------------------------------------------------------------------------
__global__ __launch_bounds__(256) void repack_kernel(const float* __restrict__ W1,
                                                     float* __restrict__ W1r)
{
    __shared__ float4 ls[4][16][32];
    const int lane = threadIdx.x & 63;
    const int w    = threadIdx.x >> 6;
    const int tile = blockIdx.x * 4 + w;          // c*64 + k
    const float4* in4  = reinterpret_cast<const float4*>(W1) + (size_t)tile * 512;
    float4*       out4 = reinterpret_cast<float4*>(W1r)      + (size_t)tile * 512;
    #pragma unroll
    for (int it = 0; it < 8; ++it) {
        const int i = it * 64 + lane;             // i = ctx*32 + p4
        ls[w][i >> 5][i & 31] = in4[i];
    }
    __syncthreads();
    #pragma unroll
    for (int it = 0; it < 8; ++it) {
        const int o = it * 64 + lane;             // o = p4*16 + ctx
        out4[o] = ls[w][o & 15][o >> 4];
    }
}

// ---------------------------------------------------------------------------
// Pack H1 into MFMA-fragment-major bf16 hi/lo planes:
//   H1f[((tile*4+q)*64 + l)*8 + e] = H1[tile*16 + (l&15)][q*32 + (l>>4)*8 + e]
// so a wave's A-fragment load is one coalesced 1KB read.
// Reads are arranged coalesced (lane -> row=(lane>>2), colchunk=(lane&3)),
// the output lane permutation l' = (lane&3)*16 + (lane>>2) scatters within 1KB.
// ---------------------------------------------------------------------------
__global__ __launch_bounds__(256) void h1pack_kernel(const float* __restrict__ H1,
                                                     short* __restrict__ H1h,
                                                     short* __restrict__ H1l)
{
    const int lane = threadIdx.x & 63;
    const int gw   = blockIdx.x * 4 + (threadIdx.x >> 6);   // tile*4 + q
    const int row  = (gw >> 2) * 16 + (lane >> 2);
    const int col  = (gw & 3) * 32 + (lane & 3) * 8;
    const float4* src = reinterpret_cast<const float4*>(H1 + (size_t)row * PP + col);
    const float4 v0 = src[0], v1 = src[1];
    const float vv[8] = {v0.x, v0.y, v0.z, v0.w, v1.x, v1.y, v1.z, v1.w};
    bf16x8 hh, ll;
    #pragma unroll
    for (int e = 0; e < 8; ++e) {
        const short hv = f2bf(vv[e]);
        hh[e] = hv;
        ll[e] = f2bf(vv[e] - bf2f(hv));
    }
    const int lp = (lane & 3) * 16 + (lane >> 2);
    const size_t o = ((size_t)gw * 64 + lp) * 8;
    *reinterpret_cast<bf16x8*>(H1h + o) = hh;
    *reinterpret_cast<bf16x8*>(H1l + o) = ll;
}

// ---------------------------------------------------------------------------
// Main predict: one block per (class-pair, 64-token tile); 2 classes/block
// share staged x and bf16 B-fragments. 3 barriers total.
// ---------------------------------------------------------------------------
__global__ __launch_bounds__(256, 4) void predict2_kernel(
    const float* __restrict__ x,
    const short* __restrict__ H1h,
    const short* __restrict__ H1l,
    const float* __restrict__ W1b,   // repacked: (c,k,p4,ctx) float4
    const float* __restrict__ H2,
    const float* __restrict__ W2,
    const float* __restrict__ fc2w,
    const float* __restrict__ fc2b,
    float* __restrict__ bout)
{
    __shared__ float xs[PP][TT + 1];          // 33280 B, stride 65
    __shared__ unsigned char ctxb[TT][68];    // 4352 B, nibbles: cls0 | cls1<<4
    __shared__ unsigned char bitb[4][TT];     // 256 B, bit0=cls0, bit1=cls1
    __shared__ float l2p[2][4][TT];           // 2048 B, per-class buffers
    // total 39936 B -> 4 blocks/CU

    const int tid  = threadIdx.x;
    const int lane = tid & 63;
    const int wid  = __builtin_amdgcn_readfirstlane(tid >> 6);
    // XCD swizzle: 1024 blocks = 8 XCD * 128; each XCD owns 4 class-pairs.
    const int bid  = blockIdx.x;
    const int sw   = ((bid & 7) << 7) | (bid >> 3);
    const int cp   = sw >> 5;                 // class pair 0..31
    const int tile = sw & (NTILES - 1);
    const int tok0 = tile * TT;
    const int c0   = cp * 2;

    // ---- stage x tile, transposed into LDS (raw f32) ---------------------
    {
        const float4* xg = reinterpret_cast<const float4*>(x + (size_t)tok0 * PP);
        #pragma unroll
        for (int it = 0; it < (TT * PP / 4) / 256; ++it) {
            const int i = it * 256 + tid;
            const float4 v = xg[i];
            const int t = i >> 5;
            const int p = (i & 31) << 2;
            xs[p + 0][t] = v.x;
            xs[p + 1][t] = v.y;
            xs[p + 2][t] = v.z;
            xs[p + 3][t] = v.w;
        }
    }
    __syncthreads();

    // ---- Phase A (MFMA): ctx nibbles for both classes --------------------
    // D layout 16x16x32: col=lane&15=token, row=4*(lane>>4)+reg.
    const int t15 = lane & 15;
    const int g   = lane >> 4;
    const int g8  = g * 8;
    const f32x4 zero4 = {0.f, 0.f, 0.f, 0.f};

    #pragma unroll
    for (int half = 0; half < 2; ++half) {
        // build B-fragments (x hi/lo) once for this half: 16 frags in regs
        bf16x8 bh[4][2], bl[4][2];
        #pragma unroll
        for (int q = 0; q < 4; ++q) {
            #pragma unroll
            for (int j2 = 0; j2 < 2; ++j2) {
                const int tok = half * 32 + j2 * 16 + t15;
                bf16x8 hb, lb;
                #pragma unroll
                for (int e = 0; e < 8; ++e) {
                    const float xv = xs[q * 32 + g8 + e][tok];
                    const short hv = f2bf(xv);
                    hb[e] = hv;
                    lb[e] = f2bf(xv - bf2f(hv));
                }
                bh[q][j2] = hb;
                bl[q][j2] = lb;
            }
        }
        int cv0[4][2];   // cls0 nibbles held until cls1 ready (one ds_write)
        #pragma unroll
        for (int cls = 0; cls < 2; ++cls) {
            const int c = c0 + cls;
            f32x4 acc[4][2];
            #pragma unroll
            for (int nt = 0; nt < 4; ++nt) { acc[nt][0] = zero4; acc[nt][1] = zero4; }
            #pragma unroll
            for (int q = 0; q < 4; ++q) {
                #pragma unroll
                for (int nt = 0; nt < 4; ++nt) {
                    const size_t fo =
                        ((((size_t)((c * 16 + wid * 4 + nt) * 4 + q)) * 64) + lane) * 8;
                    const bf16x8 ah = *reinterpret_cast<const bf16x8*>(H1h + fo);
                    const bf16x8 al = *reinterpret_cast<const bf16x8*>(H1l + fo);
                    #pragma unroll
                    for (int j2 = 0; j2 < 2; ++j2) {
                        acc[nt][j2] = __builtin_amdgcn_mfma_f32_16x16x32_bf16(ah, bh[q][j2], acc[nt][j2], 0, 0, 0);
                        acc[nt][j2] = __builtin_amdgcn_mfma_f32_16x16x32_bf16(ah, bl[q][j2], acc[nt][j2], 0, 0, 0);
                        acc[nt][j2] = __builtin_amdgcn_mfma_f32_16x16x32_bf16(al, bh[q][j2], acc[nt][j2], 0, 0, 0);
                    }
                }
            }
            #pragma unroll
            for (int nt = 0; nt < 4; ++nt) {
                #pragma unroll
                for (int j2 = 0; j2 < 2; ++j2) {
                    const int cv = (acc[nt][j2][0] > 0.f ? 1 : 0) |
                                   (acc[nt][j2][1] > 0.f ? 2 : 0) |
                                   (acc[nt][j2][2] > 0.f ? 4 : 0) |
                                   (acc[nt][j2][3] > 0.f ? 8 : 0);
                    if (cls == 0) {
                        cv0[nt][j2] = cv;
                    } else {
                        const int tok = half * 32 + j2 * 16 + t15;
                        const int k   = wid * 16 + nt * 4 + g;
                        ctxb[tok][k] = (unsigned char)(cv0[nt][j2] | (cv << 4));
                    }
                }
            }
        }
    }

    // ---- A2: wave wid computes H2 row wid sign for both classes ----------
    {
        const float4* h20 = reinterpret_cast<const float4*>(
            H2 + ((size_t)c0 * 4 + wid) * PP);
        const float4* h21 = reinterpret_cast<const float4*>(
            H2 + ((size_t)(c0 + 1) * 4 + wid) * PP);
        float d0 = 0.f, d1 = 0.f;
        #pragma unroll 8
        for (int p4 = 0; p4 < 32; ++p4) {
            const float x0 = xs[4 * p4 + 0][lane];
            const float x1 = xs[4 * p4 + 1][lane];
            const float x2 = xs[4 * p4 + 2][lane];
            const float x3 = xs[4 * p4 + 3][lane];
            const float4 w0 = h20[p4], w1 = h21[p4];
            d0 = fmaf(w0.w, x3, fmaf(w0.z, x2, fmaf(w0.y, x1, fmaf(w0.x, x0, d0))));
            d1 = fmaf(w1.w, x3, fmaf(w1.z, x2, fmaf(w1.y, x1, fmaf(w1.x, x0, d1))));
        }
        bitb[wid][lane] = (unsigned char)((d0 > 0.f ? 1 : 0) | (d1 > 0.f ? 2 : 0));
    }
    __syncthreads();   // ctxb + bitb ready; xs stays raw (clip is in-register)

    // ---- Phase B + C per class (l2p double-buffered: wave0's epilogue of
    //      class 0 overlaps waves 1-3 computing class 1) -------------------
    #pragma unroll
    for (int cls = 0; cls < 2; ++cls) {
        const int c = c0 + cls;
        const int ctx2 = ((bitb[0][lane] >> cls) & 1)       |
                         (((bitb[1][lane] >> cls) & 1) << 1) |
                         (((bitb[2][lane] >> cls) & 1) << 2) |
                         (((bitb[3][lane] >> cls) & 1) << 3);
        const float* w2 = W2 + ((size_t)c * NCTX_ + ctx2) * KK + wid * 16;
        const float4* W1c4 = reinterpret_cast<const float4*>(W1b) +
                             (size_t)(c * KK + wid * 16) * 512;
        float lp = 0.f;
        #pragma unroll
        for (int gg = 0; gg < 2; ++gg) {
            float s[8] = {0.f, 0.f, 0.f, 0.f, 0.f, 0.f, 0.f, 0.f};
            const float4* wp[8];
            #pragma unroll
            for (int j = 0; j < 8; ++j) {
                const int kk = gg * 8 + j;
                const int ctx = (ctxb[lane][wid * 16 + kk] >> (cls * 4)) & 15;
                wp[j] = W1c4 + (size_t)kk * 512 + (size_t)ctx;   // CSTRIDE=1
            }
            #pragma unroll 4
            for (int p4 = 0; p4 < 32; ++p4) {
                const float x0 = fminf(fmaxf(xs[4 * p4 + 0][lane], -5.f), 5.f);
                const float x1 = fminf(fmaxf(xs[4 * p4 + 1][lane], -5.f), 5.f);
                const float x2 = fminf(fmaxf(xs[4 * p4 + 2][lane], -5.f), 5.f);
                const float x3 = fminf(fmaxf(xs[4 * p4 + 3][lane], -5.f), 5.f);
                #pragma unroll
                for (int j = 0; j < 8; ++j) {
                    const float4 wv = wp[j][p4 * 16];            // PSTRIDE=16
                    s[j] = fmaf(wv.w, x3, fmaf(wv.z, x2,
                           fmaf(wv.y, x1, fmaf(wv.x, x0, s[j]))));
                }
            }
            #pragma unroll
            for (int j = 0; j < 8; ++j) {
                const float l1 = fminf(fmaxf(s[j], -5.f), 5.f);
                lp = fmaf(w2[gg * 8 + j], l1, lp);
            }
        }
        l2p[cls][wid][lane] = lp;
        __syncthreads();
        if (wid == 0) {
            const int t = lane;
            const float l2 = (l2p[cls][0][t] + l2p[cls][1][t]) +
                             (l2p[cls][2][t] + l2p[cls][3][t]);
            const float4* fw = reinterpret_cast<const float4*>(fc2w + (size_t)c * PP);
            float alpha = fc2b[c];
            #pragma unroll 8
            for (int p4 = 0; p4 < 32; ++p4) {
                const float4 w = fw[p4];
                alpha = fmaf(w.w, xs[4 * p4 + 3][t], fmaf(w.z, xs[4 * p4 + 2][t],
                        fmaf(w.y, xs[4 * p4 + 1][t], fmaf(w.x, xs[4 * p4 + 0][t], alpha))));
            }
            const float bv = (1.f / (1.f + expf(-l2))) * (1.f / (1.f + expf(-alpha)));
            bout[(size_t)(tok0 + t) * CC + c] = bv;
        }
    }
}

// ---------------------------------------------------------------------------
// Fallback predict (no workspace): r3-style pure-VALU kernel, 1 class/block.
// ---------------------------------------------------------------------------
template <int CSTRIDE, int PSTRIDE>
__global__ __launch_bounds__(256, 4) void predict_fb_kernel(
    const float* __restrict__ x,
    const float* __restrict__ H1,
    const float* __restrict__ W1b,
    const float* __restrict__ H2,
    const float* __restrict__ W2,
    const float* __restrict__ fc2w,
    const float* __restrict__ fc2b,
    float* __restrict__ bout)
{
    __shared__ float xs[PP][TT + 1];
    __shared__ float bitss[4][TT];
    __shared__ float apart[4][TT];
    __shared__ float l2part[4][TT];

    const int tid  = threadIdx.x;
    const int lane = tid & 63;
    const int wid  = __builtin_amdgcn_readfirstlane(tid >> 6);
    const int bid  = blockIdx.x;
    const int sw   = ((bid & 7) << 8) | (bid >> 3);
    const int c    = sw >> 5;
    const int tile = sw & (NTILES - 1);
    const int tok0 = tile * TT;

    {
        const float4* xg = reinterpret_cast<const float4*>(x + (size_t)tok0 * PP);
        #pragma unroll
        for (int it = 0; it < (TT * PP / 4) / 256; ++it) {
            const int i = it * 256 + tid;
            const float4 v = xg[i];
            const int t = i >> 5;
            const int p = (i & 31) << 2;
            xs[p + 0][t] = v.x; xs[p + 1][t] = v.y;
            xs[p + 2][t] = v.z; xs[p + 3][t] = v.w;
        }
    }
    __syncthreads();

    int ctxreg[16];
    {
        const float4* H1c4 = reinterpret_cast<const float4*>(H1 + (size_t)c * KK * 4 * PP);
        #pragma unroll
        for (int gg = 0; gg < 8; ++gg) {
            const int k = wid * 16 + gg * 2;
            const float4* h4 = H1c4 + (size_t)k * 4 * 32;
            float acc[8] = {0.f, 0.f, 0.f, 0.f, 0.f, 0.f, 0.f, 0.f};
            #pragma unroll 2
            for (int p4 = 0; p4 < 32; ++p4) {
                const float x0 = xs[4 * p4 + 0][lane];
                const float x1 = xs[4 * p4 + 1][lane];
                const float x2 = xs[4 * p4 + 2][lane];
                const float x3 = xs[4 * p4 + 3][lane];
                #pragma unroll
                for (int r = 0; r < 8; ++r) {
                    const float4 w = h4[r * 32 + p4];
                    acc[r] = fmaf(w.w, x3, fmaf(w.z, x2, fmaf(w.y, x1, fmaf(w.x, x0, acc[r]))));
                }
            }
            ctxreg[gg * 2]     = (acc[0] > 0.f ? 1 : 0) | (acc[1] > 0.f ? 2 : 0) |
                                 (acc[2] > 0.f ? 4 : 0) | (acc[3] > 0.f ? 8 : 0);
            ctxreg[gg * 2 + 1] = (acc[4] > 0.f ? 1 : 0) | (acc[5] > 0.f ? 2 : 0) |
                                 (acc[6] > 0.f ? 4 : 0) | (acc[7] > 0.f ? 8 : 0);
        }
    }
    {
        const float4* h2 = reinterpret_cast<const float4*>(H2 + ((size_t)c * 4 + wid) * PP);
        float d = 0.f;
        #pragma unroll 8
        for (int p4 = 0; p4 < 32; ++p4) {
            const float4 w = h2[p4];
            d = fmaf(w.w, xs[4 * p4 + 3][lane], fmaf(w.z, xs[4 * p4 + 2][lane],
                fmaf(w.y, xs[4 * p4 + 1][lane], fmaf(w.x, xs[4 * p4 + 0][lane], d))));
        }
        bitss[wid][lane] = (d > 0.f) ? 1.f : 0.f;
        const float4* fw = reinterpret_cast<const float4*>(fc2w + (size_t)c * PP) + wid * 8;
        float ap = 0.f;
        #pragma unroll
        for (int p4 = 0; p4 < 8; ++p4) {
            const float4 w = fw[p4];
            const int p = wid * 32 + 4 * p4;
            ap = fmaf(w.w, xs[p + 3][lane], fmaf(w.z, xs[p + 2][lane],
                 fmaf(w.y, xs[p + 1][lane], fmaf(w.x, xs[p + 0][lane], ap))));
        }
        apart[wid][lane] = ap;
    }
    __syncthreads();

    float l1v[16];
    {
        const float4* W1c4 = reinterpret_cast<const float4*>(W1b) +
                             (size_t)(c * KK + wid * 16) * 512;
        #pragma unroll
        for (int gg = 0; gg < 2; ++gg) {
            float s[8] = {0.f, 0.f, 0.f, 0.f, 0.f, 0.f, 0.f, 0.f};
            const float4* wp[8];
            #pragma unroll
            for (int j = 0; j < 8; ++j) {
                const int kk = gg * 8 + j;
                wp[j] = W1c4 + (size_t)kk * 512 + (size_t)ctxreg[kk] * CSTRIDE;
            }
            #pragma unroll 2
            for (int p4 = 0; p4 < 32; ++p4) {
                const float x0 = fminf(fmaxf(xs[4 * p4 + 0][lane], -5.f), 5.f);
                const float x1 = fminf(fmaxf(xs[4 * p4 + 1][lane], -5.f), 5.f);
                const float x2 = fminf(fmaxf(xs[4 * p4 + 2][lane], -5.f), 5.f);
                const float x3 = fminf(fmaxf(xs[4 * p4 + 3][lane], -5.f), 5.f);
                #pragma unroll
                for (int j = 0; j < 8; ++j) {
                    const float4 wv = wp[j][p4 * PSTRIDE];
                    s[j] = fmaf(wv.w, x3, fmaf(wv.z, x2, fmaf(wv.y, x1, fmaf(wv.x, x0, s[j]))));
                }
            }
            #pragma unroll
            for (int j = 0; j < 8; ++j)
                l1v[gg * 8 + j] = fminf(fmaxf(s[j], -5.f), 5.f);
        }
    }
    {
        const int ctx2 = (bitss[0][lane] > 0.5f ? 1 : 0) | (bitss[1][lane] > 0.5f ? 2 : 0) |
                         (bitss[2][lane] > 0.5f ? 4 : 0) | (bitss[3][lane] > 0.5f ? 8 : 0);
        const float* w2 = W2 + ((size_t)c * NCTX_ + ctx2) * KK + wid * 16;
        float lp = 0.f;
        #pragma unroll
        for (int j = 0; j < 16; ++j) lp = fmaf(w2[j], l1v[j], lp);
        l2part[wid][lane] = lp;
    }
    __syncthreads();
    if (wid == 0) {
        const int t = lane;
        const float l2 = (l2part[0][t] + l2part[1][t]) + (l2part[2][t] + l2part[3][t]);
        const float alpha = apart[0][t] + apart[1][t] + apart[2][t] + apart[3][t] + fc2b[c];
        const float bv = (1.f / (1.f + expf(-l2))) * (1.f / (1.f + expf(-alpha)));
        bout[(size_t)(tok0 + t) * CC + c] = bv;
    }
}

// ---------------------------------------------------------------------------
// Scan: b >= 0 and relu-outputs >= 0 => relu is identity for t >= 1, so the
// recurrence is linear: along diagonal d, acc += b_t[(d+t)&63] -- a plain
// cumsum, bit-identical ordering to the reference chain. 64-deep register
// prefetch: 8 memory stalls total instead of 512 chained latencies.
// ---------------------------------------------------------------------------
__global__ __launch_bounds__(64) void scan_kernel(const float* __restrict__ hidden,
                                                  float* __restrict__ out)
{
    const int b    = blockIdx.x;
    const int lane = threadIdx.x;
    float* row = out + (size_t)b * SS * CC;
    const float hprev = hidden[b * CC + ((lane + 63) & 63)];

    float nb[64];
    // chunk 0 (t = 0..63): t=0 is the only true relu step
    #pragma unroll
    for (int j = 0; j < 64; ++j) nb[j] = row[j * CC + ((lane + j) & 63)];
    float acc = fmaxf(nb[0] + hprev, 0.f);
    row[lane] = acc;
    #pragma unroll
    for (int j = 1; j < 64; ++j) {
        acc += nb[j];
        row[j * CC + ((lane + j) & 63)] = acc;
    }
    for (int c0 = 64; c0 < SS; c0 += 64) {
        #pragma unroll
        for (int j = 0; j < 64; ++j)
            nb[j] = row[(c0 + j) * CC + ((lane + c0 + j) & 63)];
        #pragma unroll
        for (int j = 0; j < 64; ++j) {
            acc += nb[j];
            row[(c0 + j) * CC + ((lane + c0 + j) & 63)] = acc;
        }
    }
    // h_last: lane d holds H_511 at class (d + 511) & 63
    out[(size_t)BB * SS * CC + b * CC + ((lane + 63) & 63)] = acc;
}

extern "C" void kernel_launch(void* const* d_in, const int* in_sizes, int n_in,
                              void* d_out, int out_size, void* d_ws, size_t ws_size,
                              hipStream_t stream) {
    const float* x      = (const float*)d_in[0];
    const float* hidden = (const float*)d_in[1];
    const float* H1     = (const float*)d_in[2];
    const float* W1     = (const float*)d_in[3];
    const float* H2     = (const float*)d_in[4];
    const float* W2     = (const float*)d_in[5];
    const float* fc2w   = (const float*)d_in[6];
    const float* fc2b   = (const float*)d_in[7];
    float* out = (float*)d_out;

    const size_t MB = 1024 * 1024;
    const size_t w1_bytes = (size_t)CC * KK * NCTX_ * PP * sizeof(float);   // 32 MB

    if (ws_size >= 40 * MB) {
        float* W1r = (float*)d_ws;
        short* H1h = (short*)((char*)d_ws + 32 * MB);
        short* H1l = (short*)((char*)d_ws + 36 * MB);
        repack_kernel<<<dim3(CC * KK / 4), 256, 0, stream>>>(W1, W1r);
        h1pack_kernel<<<dim3(1024), 256, 0, stream>>>(H1, H1h, H1l);
        predict2_kernel<<<dim3(CC / 2 * NTILES), 256, 0, stream>>>(
            x, H1h, H1l, W1r, H2, W2, fc2w, fc2b, out);
    } else if (ws_size >= w1_bytes) {
        float* W1r = (float*)d_ws;
        repack_kernel<<<dim3(CC * KK / 4), 256, 0, stream>>>(W1, W1r);
        predict_fb_kernel<1, 16><<<dim3(CC * NTILES), 256, 0, stream>>>(
            x, H1, W1r, H2, W2, fc2w, fc2b, out);
    } else {
        predict_fb_kernel<32, 1><<<dim3(CC * NTILES), 256, 0, stream>>>(
            x, H1, W1, H2, W2, fc2w, fc2b, out);
    }
    scan_kernel<<<dim3(BB), 64, 0, stream>>>(hidden, out);
}

// Round 6
// 296.000 us; speedup vs baseline: 1.0087x; 1.0087x over previous
//
#include <hip/hip_runtime.h>
#include <math.h>

#define BB 4
#define SS 512
#define PP 128
#define CC 64
#define KK 64
#define NCTX_ 16
#define TT 64
#define NTILES ((BB*SS)/TT)   // 32

typedef __attribute__((ext_vector_type(8))) short bf16x8;
typedef __attribute__((ext_vector_type(4))) float f32x4;

static __device__ __forceinline__ float bf2f(short h) {
    unsigned u = ((unsigned)(unsigned short)h) << 16;
    return __builtin_bit_cast(float, u);
}
static __device__ __forceinline__ short f2bf(float f) {
    unsigned u = __builtin_bit_cast(unsigned, f);
    unsigned r = (u + 0x7fffu + ((u >> 16) & 1u)) >> 16;
    return (short)(unsigned short)r;
}

// ---------------------------------------------------------------------------
// Pack H1 rows (16384 x 128 f32) into MFMA-fragment-major bf16 hi/lo planes:
//   H1f[((tile*4+q)*64 + l)*8 + e] = H1[tile*16 + (l&15)][q*32 + (l>>4)*8 + e]
// (verified in r5: coalesced 1KB fragment loads in Phase A)
// ---------------------------------------------------------------------------
__global__ __launch_bounds__(256) void h1pack_kernel(const float* __restrict__ H1,
                                                     short* __restrict__ H1h,
                                                     short* __restrict__ H1l)
{
    const int lane = threadIdx.x & 63;
    const int gw   = blockIdx.x * 4 + (threadIdx.x >> 6);   // tile*4 + q
    const int row  = (gw >> 2) * 16 + (lane >> 2);
    const int col  = (gw & 3) * 32 + (lane & 3) * 8;
    const float4* src = reinterpret_cast<const float4*>(H1 + (size_t)row * PP + col);
    const float4 v0 = src[0], v1 = src[1];
    const float vv[8] = {v0.x, v0.y, v0.z, v0.w, v1.x, v1.y, v1.z, v1.w};
    bf16x8 hh, ll;
    #pragma unroll
    for (int e = 0; e < 8; ++e) {
        const short hv = f2bf(vv[e]);
        hh[e] = hv;
        ll[e] = f2bf(vv[e] - bf2f(hv));
    }
    const int lp = (lane & 3) * 16 + (lane >> 2);
    const size_t o = ((size_t)gw * 64 + lp) * 8;
    *reinterpret_cast<bf16x8*>(H1h + o) = hh;
    *reinterpret_cast<bf16x8*>(H1l + o) = ll;
}

// ---------------------------------------------------------------------------
// Pack W1 (c,k,ctx,p) into MFMA-fragment-major bf16 hi/lo planes. One (c,k)
// slab = 16 ctx-rows x 128 p. tile = c*64+k; wave w handles q=w.
//   W1f[((tile*4+q)*64 + l)*8 + e] = W1[tile*16 + (l&15)][q*32 + (l>>4)*8 + e]
// ---------------------------------------------------------------------------
__global__ __launch_bounds__(256) void w1pack_kernel(const float* __restrict__ W1,
                                                     short* __restrict__ W1h,
                                                     short* __restrict__ W1l)
{
    const int lane = threadIdx.x & 63;
    const int q    = threadIdx.x >> 6;
    const int tile = blockIdx.x;                    // c*64 + k
    const float4* src = reinterpret_cast<const float4*>(
        W1 + ((size_t)tile * 16 + (lane >> 2)) * PP + q * 32 + (lane & 3) * 8);
    const float4 v0 = src[0], v1 = src[1];
    const float vv[8] = {v0.x, v0.y, v0.z, v0.w, v1.x, v1.y, v1.z, v1.w};
    bf16x8 hh, ll;
    #pragma unroll
    for (int e = 0; e < 8; ++e) {
        const short hv = f2bf(vv[e]);
        hh[e] = hv;
        ll[e] = f2bf(vv[e] - bf2f(hv));
    }
    const int lp = (lane & 3) * 16 + (lane >> 2);
    const size_t o = (((size_t)tile * 4 + q) * 64 + lp) * 8;
    *reinterpret_cast<bf16x8*>(W1h + o) = hh;
    *reinterpret_cast<bf16x8*>(W1l + o) = ll;
}

// ---------------------------------------------------------------------------
// Main predict: one block per (class, 64-token tile). Phase A (ctx signs) and
// Phase B (context-gated mixing) both on MFMA with packed fragment loads.
// ---------------------------------------------------------------------------
__global__ __launch_bounds__(256, 4) void predict_kernel(
    const float* __restrict__ x,
    const short* __restrict__ H1h,
    const short* __restrict__ H1l,
    const short* __restrict__ W1h,
    const short* __restrict__ W1l,
    const float* __restrict__ H2,
    const float* __restrict__ W2,
    const float* __restrict__ fc2w,
    const float* __restrict__ fc2b,
    float* __restrict__ bout)
{
    __shared__ float xs[PP][TT + 1];          // 33280 B
    __shared__ unsigned char ctxb[TT][68];    // 4352 B
    __shared__ unsigned char bitb[4][TT];     // 256 B
    __shared__ float apart[4][TT];            // 1024 B
    __shared__ float l2p[4][TT];              // 1024 B  -> 39936 B total

    const int tid  = threadIdx.x;
    const int lane = tid & 63;
    const int wid  = __builtin_amdgcn_readfirstlane(tid >> 6);
    // XCD swizzle: 2048 blocks = 8 XCD * 256; each XCD owns 8 classes.
    const int bid  = blockIdx.x;
    const int sw   = ((bid & 7) << 8) | (bid >> 3);
    const int c    = sw >> 5;
    const int tile = sw & (NTILES - 1);
    const int tok0 = tile * TT;

    const int t15 = lane & 15;
    const int g   = lane >> 4;
    const int g8  = g * 8;
    const f32x4 zero4 = {0.f, 0.f, 0.f, 0.f};

    // ---- stage x tile, transposed into LDS (raw f32) ---------------------
    {
        const float4* xg = reinterpret_cast<const float4*>(x + (size_t)tok0 * PP);
        #pragma unroll
        for (int it = 0; it < (TT * PP / 4) / 256; ++it) {
            const int i = it * 256 + tid;
            const float4 v = xg[i];
            const int t = i >> 5;
            const int p = (i & 31) << 2;
            xs[p + 0][t] = v.x;
            xs[p + 1][t] = v.y;
            xs[p + 2][t] = v.z;
            xs[p + 3][t] = v.w;
        }
    }
    __syncthreads();

    // ---- Phase A (MFMA): ctx nibbles, r4 structure + packed frag loads ---
    const int ctile = c * 16 + wid * 4;
    #pragma unroll
    for (int half = 0; half < 2; ++half) {
        f32x4 acc[4][2];
        #pragma unroll
        for (int nt = 0; nt < 4; ++nt) { acc[nt][0] = zero4; acc[nt][1] = zero4; }
        #pragma unroll
        for (int q = 0; q < 4; ++q) {
            bf16x8 bh[2], bl[2];
            #pragma unroll
            for (int j2 = 0; j2 < 2; ++j2) {
                const int tok = half * 32 + j2 * 16 + t15;
                bf16x8 hb, lb;
                #pragma unroll
                for (int e = 0; e < 8; ++e) {
                    const float xv = xs[q * 32 + g8 + e][tok];
                    const short hv = f2bf(xv);
                    hb[e] = hv;
                    lb[e] = f2bf(xv - bf2f(hv));
                }
                bh[j2] = hb; bl[j2] = lb;
            }
            #pragma unroll
            for (int nt = 0; nt < 4; ++nt) {
                const size_t fo = (((size_t)(ctile + nt) * 4 + q) * 64 + lane) * 8;
                const bf16x8 ah = *reinterpret_cast<const bf16x8*>(H1h + fo);
                const bf16x8 al = *reinterpret_cast<const bf16x8*>(H1l + fo);
                #pragma unroll
                for (int j2 = 0; j2 < 2; ++j2) {
                    acc[nt][j2] = __builtin_amdgcn_mfma_f32_16x16x32_bf16(ah, bh[j2], acc[nt][j2], 0, 0, 0);
                    acc[nt][j2] = __builtin_amdgcn_mfma_f32_16x16x32_bf16(ah, bl[j2], acc[nt][j2], 0, 0, 0);
                    acc[nt][j2] = __builtin_amdgcn_mfma_f32_16x16x32_bf16(al, bh[j2], acc[nt][j2], 0, 0, 0);
                }
            }
        }
        #pragma unroll
        for (int nt = 0; nt < 4; ++nt) {
            #pragma unroll
            for (int j2 = 0; j2 < 2; ++j2) {
                const int tok = half * 32 + j2 * 16 + t15;
                const int k   = wid * 16 + nt * 4 + g;
                const int cv  = (acc[nt][j2][0] > 0.f ? 1 : 0) |
                                (acc[nt][j2][1] > 0.f ? 2 : 0) |
                                (acc[nt][j2][2] > 0.f ? 4 : 0) |
                                (acc[nt][j2][3] > 0.f ? 8 : 0);
                ctxb[tok][k] = (unsigned char)cv;
            }
        }
    }

    // ---- A2: H2 sign (wave wid = bit wid) + alpha partial ----------------
    {
        const float4* h2 = reinterpret_cast<const float4*>(
            H2 + ((size_t)c * 4 + wid) * PP);
        float d = 0.f;
        #pragma unroll 8
        for (int p4 = 0; p4 < 32; ++p4) {
            const float4 w = h2[p4];
            d = fmaf(w.w, xs[4 * p4 + 3][lane], fmaf(w.z, xs[4 * p4 + 2][lane],
                fmaf(w.y, xs[4 * p4 + 1][lane], fmaf(w.x, xs[4 * p4 + 0][lane], d))));
        }
        bitb[wid][lane] = (unsigned char)(d > 0.f ? 1 : 0);

        const float4* fw = reinterpret_cast<const float4*>(fc2w + (size_t)c * PP) + wid * 8;
        float ap = 0.f;
        #pragma unroll
        for (int p4 = 0; p4 < 8; ++p4) {
            const float4 w = fw[p4];
            const int p = wid * 32 + 4 * p4;
            ap = fmaf(w.w, xs[p + 3][lane], fmaf(w.z, xs[p + 2][lane],
                 fmaf(w.y, xs[p + 1][lane], fmaf(w.x, xs[p + 0][lane], ap))));
        }
        apart[wid][lane] = ap;
    }
    __syncthreads();   // bitb/apart cross-wave; ctxb is same-wave for Phase B

    // ---- Phase B (MFMA): all-ctx mixes per k, in-register selection ------
    // Wave wid owns k = wid*16..+15. Per token-tile j: rows of W1f tile k are
    // exactly the 16 contexts; lane (g,t15) reg r holds mix[tok=j*16+t15][ctx=4g+r].
    #pragma unroll
    for (int j = 0; j < 4; ++j) {
        const int tok = j * 16 + t15;
        // clipped-x B-fragments for this token-tile
        bf16x8 ch[4], cl[4];
        #pragma unroll
        for (int q = 0; q < 4; ++q) {
            bf16x8 hb, lb;
            #pragma unroll
            for (int e = 0; e < 8; ++e) {
                const float xv = fminf(fmaxf(xs[q * 32 + g8 + e][tok], -5.f), 5.f);
                const short hv = f2bf(xv);
                hb[e] = hv;
                lb[e] = f2bf(xv - bf2f(hv));
            }
            ch[q] = hb; cl[q] = lb;
        }
        // W2 row for this token (ctx2 gathers 64B contiguous)
        const int ctx2 = bitb[0][tok] | (bitb[1][tok] << 1) |
                         (bitb[2][tok] << 2) | (bitb[3][tok] << 3);
        const float4* w2p = reinterpret_cast<const float4*>(
            W2 + ((size_t)c * NCTX_ + ctx2) * KK + wid * 16);
        const float4 wa = w2p[0], wb = w2p[1], wc = w2p[2], wd = w2p[3];
        const float w2v[16] = {wa.x, wa.y, wa.z, wa.w, wb.x, wb.y, wb.z, wb.w,
                               wc.x, wc.y, wc.z, wc.w, wd.x, wd.y, wd.z, wd.w};
        float lp = 0.f;
        #pragma unroll
        for (int k16 = 0; k16 < 16; ++k16) {
            const int k = wid * 16 + k16;
            f32x4 acc = zero4;
            #pragma unroll
            for (int q = 0; q < 4; ++q) {
                const size_t fo = (((size_t)(c * KK + k) * 4 + q) * 64 + lane) * 8;
                const bf16x8 ah = *reinterpret_cast<const bf16x8*>(W1h + fo);
                const bf16x8 al = *reinterpret_cast<const bf16x8*>(W1l + fo);
                acc = __builtin_amdgcn_mfma_f32_16x16x32_bf16(ah, ch[q], acc, 0, 0, 0);
                acc = __builtin_amdgcn_mfma_f32_16x16x32_bf16(ah, cl[q], acc, 0, 0, 0);
                acc = __builtin_amdgcn_mfma_f32_16x16x32_bf16(al, ch[q], acc, 0, 0, 0);
            }
            // select ctx1[tok][k] and broadcast across the 4 g-groups
            const int cx  = ctxb[tok][k];
            const int sel = cx & 3;
            float v = (sel == 0) ? acc[0] : (sel == 1) ? acc[1] :
                      (sel == 2) ? acc[2] : acc[3];
            v = (g == (cx >> 2)) ? v : 0.f;
            v += __shfl_xor(v, 16, 64);
            v += __shfl_xor(v, 32, 64);
            const float l1 = fminf(fmaxf(v, -5.f), 5.f);
            lp = fmaf(w2v[k16], l1, lp);
        }
        if (g == 0) l2p[wid][tok] = lp;
    }
    __syncthreads();

    // ---- epilogue --------------------------------------------------------
    if (wid == 0) {
        const int t = lane;
        const float l2 = (l2p[0][t] + l2p[1][t]) + (l2p[2][t] + l2p[3][t]);
        const float alpha = apart[0][t] + apart[1][t] + apart[2][t] + apart[3][t] + fc2b[c];
        const float bv = (1.f / (1.f + expf(-l2))) * (1.f / (1.f + expf(-alpha)));
        bout[(size_t)(tok0 + t) * CC + c] = bv;
    }
}

// ---------------------------------------------------------------------------
// Fallback predict (small workspace): r3-style pure-VALU kernel.
// ---------------------------------------------------------------------------
__global__ __launch_bounds__(256, 4) void predict_fb_kernel(
    const float* __restrict__ x,
    const float* __restrict__ H1,
    const float* __restrict__ W1b,   // original layout (ctx*32 + p4)
    const float* __restrict__ H2,
    const float* __restrict__ W2,
    const float* __restrict__ fc2w,
    const float* __restrict__ fc2b,
    float* __restrict__ bout)
{
    __shared__ float xs[PP][TT + 1];
    __shared__ float bitss[4][TT];
    __shared__ float apart[4][TT];
    __shared__ float l2part[4][TT];

    const int tid  = threadIdx.x;
    const int lane = tid & 63;
    const int wid  = __builtin_amdgcn_readfirstlane(tid >> 6);
    const int bid  = blockIdx.x;
    const int sw   = ((bid & 7) << 8) | (bid >> 3);
    const int c    = sw >> 5;
    const int tile = sw & (NTILES - 1);
    const int tok0 = tile * TT;

    {
        const float4* xg = reinterpret_cast<const float4*>(x + (size_t)tok0 * PP);
        #pragma unroll
        for (int it = 0; it < (TT * PP / 4) / 256; ++it) {
            const int i = it * 256 + tid;
            const float4 v = xg[i];
            const int t = i >> 5;
            const int p = (i & 31) << 2;
            xs[p + 0][t] = v.x; xs[p + 1][t] = v.y;
            xs[p + 2][t] = v.z; xs[p + 3][t] = v.w;
        }
    }
    __syncthreads();

    int ctxreg[16];
    {
        const float4* H1c4 = reinterpret_cast<const float4*>(H1 + (size_t)c * KK * 4 * PP);
        #pragma unroll
        for (int gg = 0; gg < 8; ++gg) {
            const int k = wid * 16 + gg * 2;
            const float4* h4 = H1c4 + (size_t)k * 4 * 32;
            float acc[8] = {0.f, 0.f, 0.f, 0.f, 0.f, 0.f, 0.f, 0.f};
            #pragma unroll 2
            for (int p4 = 0; p4 < 32; ++p4) {
                const float x0 = xs[4 * p4 + 0][lane];
                const float x1 = xs[4 * p4 + 1][lane];
                const float x2 = xs[4 * p4 + 2][lane];
                const float x3 = xs[4 * p4 + 3][lane];
                #pragma unroll
                for (int r = 0; r < 8; ++r) {
                    const float4 w = h4[r * 32 + p4];
                    acc[r] = fmaf(w.w, x3, fmaf(w.z, x2, fmaf(w.y, x1, fmaf(w.x, x0, acc[r]))));
                }
            }
            ctxreg[gg * 2]     = (acc[0] > 0.f ? 1 : 0) | (acc[1] > 0.f ? 2 : 0) |
                                 (acc[2] > 0.f ? 4 : 0) | (acc[3] > 0.f ? 8 : 0);
            ctxreg[gg * 2 + 1] = (acc[4] > 0.f ? 1 : 0) | (acc[5] > 0.f ? 2 : 0) |
                                 (acc[6] > 0.f ? 4 : 0) | (acc[7] > 0.f ? 8 : 0);
        }
    }
    {
        const float4* h2 = reinterpret_cast<const float4*>(H2 + ((size_t)c * 4 + wid) * PP);
        float d = 0.f;
        #pragma unroll 8
        for (int p4 = 0; p4 < 32; ++p4) {
            const float4 w = h2[p4];
            d = fmaf(w.w, xs[4 * p4 + 3][lane], fmaf(w.z, xs[4 * p4 + 2][lane],
                fmaf(w.y, xs[4 * p4 + 1][lane], fmaf(w.x, xs[4 * p4 + 0][lane], d))));
        }
        bitss[wid][lane] = (d > 0.f) ? 1.f : 0.f;
        const float4* fw = reinterpret_cast<const float4*>(fc2w + (size_t)c * PP) + wid * 8;
        float ap = 0.f;
        #pragma unroll
        for (int p4 = 0; p4 < 8; ++p4) {
            const float4 w = fw[p4];
            const int p = wid * 32 + 4 * p4;
            ap = fmaf(w.w, xs[p + 3][lane], fmaf(w.z, xs[p + 2][lane],
                 fmaf(w.y, xs[p + 1][lane], fmaf(w.x, xs[p + 0][lane], ap))));
        }
        apart[wid][lane] = ap;
    }
    __syncthreads();

    float l1v[16];
    {
        const float4* W1c4 = reinterpret_cast<const float4*>(W1b) +
                             (size_t)(c * KK + wid * 16) * 512;
        #pragma unroll
        for (int gg = 0; gg < 2; ++gg) {
            float s[8] = {0.f, 0.f, 0.f, 0.f, 0.f, 0.f, 0.f, 0.f};
            const float4* wp[8];
            #pragma unroll
            for (int jj = 0; jj < 8; ++jj) {
                const int kk = gg * 8 + jj;
                wp[jj] = W1c4 + (size_t)kk * 512 + (size_t)ctxreg[kk] * 32;
            }
            #pragma unroll 2
            for (int p4 = 0; p4 < 32; ++p4) {
                const float x0 = fminf(fmaxf(xs[4 * p4 + 0][lane], -5.f), 5.f);
                const float x1 = fminf(fmaxf(xs[4 * p4 + 1][lane], -5.f), 5.f);
                const float x2 = fminf(fmaxf(xs[4 * p4 + 2][lane], -5.f), 5.f);
                const float x3 = fminf(fmaxf(xs[4 * p4 + 3][lane], -5.f), 5.f);
                #pragma unroll
                for (int jj = 0; jj < 8; ++jj) {
                    const float4 wv = wp[jj][p4];
                    s[jj] = fmaf(wv.w, x3, fmaf(wv.z, x2, fmaf(wv.y, x1, fmaf(wv.x, x0, s[jj]))));
                }
            }
            #pragma unroll
            for (int jj = 0; jj < 8; ++jj)
                l1v[gg * 8 + jj] = fminf(fmaxf(s[jj], -5.f), 5.f);
        }
    }
    {
        const int ctx2 = (bitss[0][lane] > 0.5f ? 1 : 0) | (bitss[1][lane] > 0.5f ? 2 : 0) |
                         (bitss[2][lane] > 0.5f ? 4 : 0) | (bitss[3][lane] > 0.5f ? 8 : 0);
        const float* w2 = W2 + ((size_t)c * NCTX_ + ctx2) * KK + wid * 16;
        float lp = 0.f;
        #pragma unroll
        for (int jj = 0; jj < 16; ++jj) lp = fmaf(w2[jj], l1v[jj], lp);
        l2part[wid][lane] = lp;
    }
    __syncthreads();
    if (wid == 0) {
        const int t = lane;
        const float l2 = (l2part[0][t] + l2part[1][t]) + (l2part[2][t] + l2part[3][t]);
        const float alpha = apart[0][t] + apart[1][t] + apart[2][t] + apart[3][t] + fc2b[c];
        const float bv = (1.f / (1.f + expf(-l2))) * (1.f / (1.f + expf(-alpha)));
        bout[(size_t)(tok0 + t) * CC + c] = bv;
    }
}

// ---------------------------------------------------------------------------
// Scan: b > 0 and relu-outputs >= 0 => relu is identity for t >= 1; along
// diagonal d the recurrence is a plain cumsum (bit-identical ordering).
// ---------------------------------------------------------------------------
__global__ __launch_bounds__(64) void scan_kernel(const float* __restrict__ hidden,
                                                  float* __restrict__ out)
{
    const int b    = blockIdx.x;
    const int lane = threadIdx.x;
    float* row = out + (size_t)b * SS * CC;
    const float hprev = hidden[b * CC + ((lane + 63) & 63)];

    float nb[64];
    #pragma unroll
    for (int j = 0; j < 64; ++j) nb[j] = row[j * CC + ((lane + j) & 63)];
    float acc = fmaxf(nb[0] + hprev, 0.f);
    row[lane] = acc;
    #pragma unroll
    for (int j = 1; j < 64; ++j) {
        acc += nb[j];
        row[j * CC + ((lane + j) & 63)] = acc;
    }
    for (int c0 = 64; c0 < SS; c0 += 64) {
        #pragma unroll
        for (int j = 0; j < 64; ++j)
            nb[j] = row[(c0 + j) * CC + ((lane + c0 + j) & 63)];
        #pragma unroll
        for (int j = 0; j < 64; ++j) {
            acc += nb[j];
            row[(c0 + j) * CC + ((lane + c0 + j) & 63)] = acc;
        }
    }
    out[(size_t)BB * SS * CC + b * CC + ((lane + 63) & 63)] = acc;
}

extern "C" void kernel_launch(void* const* d_in, const int* in_sizes, int n_in,
                              void* d_out, int out_size, void* d_ws, size_t ws_size,
                              hipStream_t stream) {
    const float* x      = (const float*)d_in[0];
    const float* hidden = (const float*)d_in[1];
    const float* H1     = (const float*)d_in[2];
    const float* W1     = (const float*)d_in[3];
    const float* H2     = (const float*)d_in[4];
    const float* W2     = (const float*)d_in[5];
    const float* fc2w   = (const float*)d_in[6];
    const float* fc2b   = (const float*)d_in[7];
    float* out = (float*)d_out;

    const size_t MB = 1024 * 1024;

    if (ws_size >= 40 * MB) {
        // layout: W1h[16MB] | W1l[16MB] | H1h[4MB] | H1l[4MB]
        short* W1hp = (short*)d_ws;
        short* W1lp = (short*)((char*)d_ws + 16 * MB);
        short* H1hp = (short*)((char*)d_ws + 32 * MB);
        short* H1lp = (short*)((char*)d_ws + 36 * MB);
        w1pack_kernel<<<dim3(CC * KK), 256, 0, stream>>>(W1, W1hp, W1lp);
        h1pack_kernel<<<dim3(1024), 256, 0, stream>>>(H1, H1hp, H1lp);
        predict_kernel<<<dim3(CC * NTILES), 256, 0, stream>>>(
            x, H1hp, H1lp, W1hp, W1lp, H2, W2, fc2w, fc2b, out);
    } else {
        predict_fb_kernel<<<dim3(CC * NTILES), 256, 0, stream>>>(
            x, H1, W1, H2, W2, fc2w, fc2b, out);
    }
    scan_kernel<<<dim3(BB), 64, 0, stream>>>(hidden, out);
}

// Round 7
// 168.629 us; speedup vs baseline: 1.7706x; 1.7553x over previous
//
#include <hip/hip_runtime.h>
#include <math.h>

#define BB 4
#define SS 512
#define PP 128
#define CC 64
#define KK 64
#define NCTX_ 16
#define TT 64
#define NTILES ((BB*SS)/TT)   // 32

typedef __attribute__((ext_vector_type(8))) short bf16x8;
typedef __attribute__((ext_vector_type(4))) float f32x4;

static __device__ __forceinline__ float bf2f(short h) {
    unsigned u = ((unsigned)(unsigned short)h) << 16;
    return __builtin_bit_cast(float, u);
}
static __device__ __forceinline__ short f2bf(float f) {
    unsigned u = __builtin_bit_cast(unsigned, f);
    unsigned r = (u + 0x7fffu + ((u >> 16) & 1u)) >> 16;
    return (short)(unsigned short)r;
}

// ---------------------------------------------------------------------------
// Pack H1 rows (16384 x 128 f32) into MFMA-fragment-major bf16 hi/lo planes:
//   H1f[((tile*4+q)*64 + l)*8 + e] = H1[tile*16 + (l&15)][q*32 + (l>>4)*8 + e]
// ---------------------------------------------------------------------------
__global__ __launch_bounds__(256) void h1pack_kernel(const float* __restrict__ H1,
                                                     short* __restrict__ H1h,
                                                     short* __restrict__ H1l)
{
    const int lane = threadIdx.x & 63;
    const int gw   = blockIdx.x * 4 + (threadIdx.x >> 6);   // tile*4 + q
    const int row  = (gw >> 2) * 16 + (lane >> 2);
    const int col  = (gw & 3) * 32 + (lane & 3) * 8;
    const float4* src = reinterpret_cast<const float4*>(H1 + (size_t)row * PP + col);
    const float4 v0 = src[0], v1 = src[1];
    const float vv[8] = {v0.x, v0.y, v0.z, v0.w, v1.x, v1.y, v1.z, v1.w};
    bf16x8 hh, ll;
    #pragma unroll
    for (int e = 0; e < 8; ++e) {
        const short hv = f2bf(vv[e]);
        hh[e] = hv;
        ll[e] = f2bf(vv[e] - bf2f(hv));
    }
    const int lp = (lane & 3) * 16 + (lane >> 2);
    const size_t o = ((size_t)gw * 64 + lp) * 8;
    *reinterpret_cast<bf16x8*>(H1h + o) = hh;
    *reinterpret_cast<bf16x8*>(H1l + o) = ll;
}

// ---------------------------------------------------------------------------
// Pack W1 (c,k,ctx,p) into MFMA-fragment-major bf16 (hi plane only, 16 MB):
//   W1f[((tile*4+q)*64 + l)*8 + e] = W1[tile*16 + (l&15)][q*32 + (l>>4)*8 + e]
// ---------------------------------------------------------------------------
__global__ __launch_bounds__(256) void w1pack_kernel(const float* __restrict__ W1,
                                                     short* __restrict__ W1h)
{
    const int lane = threadIdx.x & 63;
    const int q    = threadIdx.x >> 6;
    const int tile = blockIdx.x;                    // c*64 + k
    const float4* src = reinterpret_cast<const float4*>(
        W1 + ((size_t)tile * 16 + (lane >> 2)) * PP + q * 32 + (lane & 3) * 8);
    const float4 v0 = src[0], v1 = src[1];
    const float vv[8] = {v0.x, v0.y, v0.z, v0.w, v1.x, v1.y, v1.z, v1.w};
    bf16x8 hh;
    #pragma unroll
    for (int e = 0; e < 8; ++e) hh[e] = f2bf(vv[e]);
    const int lp = (lane & 3) * 16 + (lane >> 2);
    const size_t o = (((size_t)tile * 4 + q) * 64 + lp) * 8;
    *reinterpret_cast<bf16x8*>(W1h + o) = hh;
}

// ---------------------------------------------------------------------------
// Main predict: one block per (class, 64-token tile).
// Phase A: 3-pass split-bf16 MFMA (sign precision). Phase B: 1-pass bf16 MFMA
// over all 16 contexts, in-register selection, 2-token-tile reuse of W1h.
// ---------------------------------------------------------------------------
__global__ __launch_bounds__(256, 4) void predict_kernel(
    const float* __restrict__ x,
    const short* __restrict__ H1h,
    const short* __restrict__ H1l,
    const short* __restrict__ W1h,
    const float* __restrict__ H2,
    const float* __restrict__ W2,
    const float* __restrict__ fc2w,
    const float* __restrict__ fc2b,
    float* __restrict__ bout)
{
    __shared__ float xs[PP][TT + 1];          // 33280 B
    __shared__ unsigned char ctxb[TT][68];    // 4352 B
    __shared__ unsigned char bitb[4][TT];     // 256 B
    __shared__ float apart[4][TT];            // 1024 B
    __shared__ float l2p[4][TT];              // 1024 B  -> 39936 B total

    const int tid  = threadIdx.x;
    const int lane = tid & 63;
    const int wid  = __builtin_amdgcn_readfirstlane(tid >> 6);
    // XCD swizzle: 2048 blocks = 8 XCD * 256; each XCD owns 8 classes.
    const int bid  = blockIdx.x;
    const int sw   = ((bid & 7) << 8) | (bid >> 3);
    const int c    = sw >> 5;
    const int tile = sw & (NTILES - 1);
    const int tok0 = tile * TT;

    const int t15 = lane & 15;
    const int g   = lane >> 4;
    const int g8  = g * 8;
    const f32x4 zero4 = {0.f, 0.f, 0.f, 0.f};

    // ---- stage x tile, transposed into LDS (raw f32) ---------------------
    {
        const float4* xg = reinterpret_cast<const float4*>(x + (size_t)tok0 * PP);
        #pragma unroll
        for (int it = 0; it < (TT * PP / 4) / 256; ++it) {
            const int i = it * 256 + tid;
            const float4 v = xg[i];
            const int t = i >> 5;
            const int p = (i & 31) << 2;
            xs[p + 0][t] = v.x;
            xs[p + 1][t] = v.y;
            xs[p + 2][t] = v.z;
            xs[p + 3][t] = v.w;
        }
    }
    __syncthreads();

    // ---- Phase A (MFMA, 3-pass): ctx nibbles -----------------------------
    const int ctile = c * 16 + wid * 4;
    #pragma unroll
    for (int half = 0; half < 2; ++half) {
        f32x4 acc[4][2];
        #pragma unroll
        for (int nt = 0; nt < 4; ++nt) { acc[nt][0] = zero4; acc[nt][1] = zero4; }
        #pragma unroll
        for (int q = 0; q < 4; ++q) {
            bf16x8 bh[2], bl[2];
            #pragma unroll
            for (int j2 = 0; j2 < 2; ++j2) {
                const int tok = half * 32 + j2 * 16 + t15;
                bf16x8 hb, lb;
                #pragma unroll
                for (int e = 0; e < 8; ++e) {
                    const float xv = xs[q * 32 + g8 + e][tok];
                    const short hv = f2bf(xv);
                    hb[e] = hv;
                    lb[e] = f2bf(xv - bf2f(hv));
                }
                bh[j2] = hb; bl[j2] = lb;
            }
            #pragma unroll
            for (int nt = 0; nt < 4; ++nt) {
                const size_t fo = (((size_t)(ctile + nt) * 4 + q) * 64 + lane) * 8;
                const bf16x8 ah = *reinterpret_cast<const bf16x8*>(H1h + fo);
                const bf16x8 al = *reinterpret_cast<const bf16x8*>(H1l + fo);
                #pragma unroll
                for (int j2 = 0; j2 < 2; ++j2) {
                    acc[nt][j2] = __builtin_amdgcn_mfma_f32_16x16x32_bf16(ah, bh[j2], acc[nt][j2], 0, 0, 0);
                    acc[nt][j2] = __builtin_amdgcn_mfma_f32_16x16x32_bf16(ah, bl[j2], acc[nt][j2], 0, 0, 0);
                    acc[nt][j2] = __builtin_amdgcn_mfma_f32_16x16x32_bf16(al, bh[j2], acc[nt][j2], 0, 0, 0);
                }
            }
        }
        #pragma unroll
        for (int nt = 0; nt < 4; ++nt) {
            #pragma unroll
            for (int j2 = 0; j2 < 2; ++j2) {
                const int tok = half * 32 + j2 * 16 + t15;
                const int k   = wid * 16 + nt * 4 + g;
                const int cv  = (acc[nt][j2][0] > 0.f ? 1 : 0) |
                                (acc[nt][j2][1] > 0.f ? 2 : 0) |
                                (acc[nt][j2][2] > 0.f ? 4 : 0) |
                                (acc[nt][j2][3] > 0.f ? 8 : 0);
                ctxb[tok][k] = (unsigned char)cv;
            }
        }
    }

    // ---- A2: H2 sign (wave wid = bit wid) + alpha partial ----------------
    {
        const float4* h2 = reinterpret_cast<const float4*>(
            H2 + ((size_t)c * 4 + wid) * PP);
        float d = 0.f;
        #pragma unroll 8
        for (int p4 = 0; p4 < 32; ++p4) {
            const float4 w = h2[p4];
            d = fmaf(w.w, xs[4 * p4 + 3][lane], fmaf(w.z, xs[4 * p4 + 2][lane],
                fmaf(w.y, xs[4 * p4 + 1][lane], fmaf(w.x, xs[4 * p4 + 0][lane], d))));
        }
        bitb[wid][lane] = (unsigned char)(d > 0.f ? 1 : 0);

        const float4* fw = reinterpret_cast<const float4*>(fc2w + (size_t)c * PP) + wid * 8;
        float ap = 0.f;
        #pragma unroll
        for (int p4 = 0; p4 < 8; ++p4) {
            const float4 w = fw[p4];
            const int p = wid * 32 + 4 * p4;
            ap = fmaf(w.w, xs[p + 3][lane], fmaf(w.z, xs[p + 2][lane],
                 fmaf(w.y, xs[p + 1][lane], fmaf(w.x, xs[p + 0][lane], ap))));
        }
        apart[wid][lane] = ap;
    }
    __syncthreads();   // bitb cross-wave; ctxb same-wave for Phase B

    // ---- Phase B (MFMA, 1-pass bf16): 2 token-tiles per W1h fragment -----
    // Wave wid owns k = wid*16..+15; W1f tile rows = the 16 contexts.
    // Lane (g,t15) reg r holds mix[tok][ctx=4g+r].
    #pragma unroll
    for (int jp = 0; jp < 2; ++jp) {
        const int tokA = jp * 32 + t15;
        const int tokB = jp * 32 + 16 + t15;
        // clipped-x bf16 fragments for the 2 token-tiles (hi only)
        bf16x8 chA[4], chB[4];
        #pragma unroll
        for (int q = 0; q < 4; ++q) {
            bf16x8 ha, hb;
            #pragma unroll
            for (int e = 0; e < 8; ++e) {
                const float xa = fminf(fmaxf(xs[q * 32 + g8 + e][tokA], -5.f), 5.f);
                const float xb = fminf(fmaxf(xs[q * 32 + g8 + e][tokB], -5.f), 5.f);
                ha[e] = f2bf(xa);
                hb[e] = f2bf(xb);
            }
            chA[q] = ha; chB[q] = hb;
        }
        // W2 rows for both tokens (ctx2-gathered, 64B contiguous)
        const int ctxA = bitb[0][tokA] | (bitb[1][tokA] << 1) |
                         (bitb[2][tokA] << 2) | (bitb[3][tokA] << 3);
        const int ctxB = bitb[0][tokB] | (bitb[1][tokB] << 1) |
                         (bitb[2][tokB] << 2) | (bitb[3][tokB] << 3);
        const float4* wpa = reinterpret_cast<const float4*>(
            W2 + ((size_t)c * NCTX_ + ctxA) * KK + wid * 16);
        const float4* wpb = reinterpret_cast<const float4*>(
            W2 + ((size_t)c * NCTX_ + ctxB) * KK + wid * 16);
        float4 w2qA[4] = {wpa[0], wpa[1], wpa[2], wpa[3]};
        float4 w2qB[4] = {wpb[0], wpb[1], wpb[2], wpb[3]};

        float lpA = 0.f, lpB = 0.f;
        #pragma unroll
        for (int k16 = 0; k16 < 16; ++k16) {
            const int k = wid * 16 + k16;
            f32x4 aA = zero4, aB = zero4;
            #pragma unroll
            for (int q = 0; q < 4; ++q) {
                const size_t fo = (((size_t)(c * KK + k) * 4 + q) * 64 + lane) * 8;
                const bf16x8 ah = *reinterpret_cast<const bf16x8*>(W1h + fo);
                aA = __builtin_amdgcn_mfma_f32_16x16x32_bf16(ah, chA[q], aA, 0, 0, 0);
                aB = __builtin_amdgcn_mfma_f32_16x16x32_bf16(ah, chB[q], aB, 0, 0, 0);
            }
            // ctx selection + cross-group broadcast + W2 accumulate
            {
                const int cx  = ctxb[tokA][k];
                const int sel = cx & 3;
                float v = (sel == 0) ? aA[0] : (sel == 1) ? aA[1] :
                          (sel == 2) ? aA[2] : aA[3];
                v = (g == (cx >> 2)) ? v : 0.f;
                v += __shfl_xor(v, 16, 64);
                v += __shfl_xor(v, 32, 64);
                const float wv = ((const float*)&w2qA[k16 >> 2])[k16 & 3];
                lpA = fmaf(wv, fminf(fmaxf(v, -5.f), 5.f), lpA);
            }
            {
                const int cx  = ctxb[tokB][k];
                const int sel = cx & 3;
                float v = (sel == 0) ? aB[0] : (sel == 1) ? aB[1] :
                          (sel == 2) ? aB[2] : aB[3];
                v = (g == (cx >> 2)) ? v : 0.f;
                v += __shfl_xor(v, 16, 64);
                v += __shfl_xor(v, 32, 64);
                const float wv = ((const float*)&w2qB[k16 >> 2])[k16 & 3];
                lpB = fmaf(wv, fminf(fmaxf(v, -5.f), 5.f), lpB);
            }
        }
        if (g == 0) {
            l2p[wid][tokA] = lpA;
            l2p[wid][tokB] = lpB;
        }
    }
    __syncthreads();

    // ---- epilogue --------------------------------------------------------
    if (wid == 0) {
        const int t = lane;
        const float l2 = (l2p[0][t] + l2p[1][t]) + (l2p[2][t] + l2p[3][t]);
        const float alpha = apart[0][t] + apart[1][t] + apart[2][t] + apart[3][t] + fc2b[c];
        const float bv = (1.f / (1.f + expf(-l2))) * (1.f / (1.f + expf(-alpha)));
        bout[(size_t)(tok0 + t) * CC + c] = bv;
    }
}

// ---------------------------------------------------------------------------
// Fallback predict (small workspace): pure-VALU kernel on original layouts.
// ---------------------------------------------------------------------------
__global__ __launch_bounds__(256, 4) void predict_fb_kernel(
    const float* __restrict__ x,
    const float* __restrict__ H1,
    const float* __restrict__ W1b,   // original layout (ctx*32 + p4)
    const float* __restrict__ H2,
    const float* __restrict__ W2,
    const float* __restrict__ fc2w,
    const float* __restrict__ fc2b,
    float* __restrict__ bout)
{
    __shared__ float xs[PP][TT + 1];
    __shared__ float bitss[4][TT];
    __shared__ float apart[4][TT];
    __shared__ float l2part[4][TT];

    const int tid  = threadIdx.x;
    const int lane = tid & 63;
    const int wid  = __builtin_amdgcn_readfirstlane(tid >> 6);
    const int bid  = blockIdx.x;
    const int sw   = ((bid & 7) << 8) | (bid >> 3);
    const int c    = sw >> 5;
    const int tile = sw & (NTILES - 1);
    const int tok0 = tile * TT;

    {
        const float4* xg = reinterpret_cast<const float4*>(x + (size_t)tok0 * PP);
        #pragma unroll
        for (int it = 0; it < (TT * PP / 4) / 256; ++it) {
            const int i = it * 256 + tid;
            const float4 v = xg[i];
            const int t = i >> 5;
            const int p = (i & 31) << 2;
            xs[p + 0][t] = v.x; xs[p + 1][t] = v.y;
            xs[p + 2][t] = v.z; xs[p + 3][t] = v.w;
        }
    }
    __syncthreads();

    int ctxreg[16];
    {
        const float4* H1c4 = reinterpret_cast<const float4*>(H1 + (size_t)c * KK * 4 * PP);
        #pragma unroll
        for (int gg = 0; gg < 8; ++gg) {
            const int k = wid * 16 + gg * 2;
            const float4* h4 = H1c4 + (size_t)k * 4 * 32;
            float acc[8] = {0.f, 0.f, 0.f, 0.f, 0.f, 0.f, 0.f, 0.f};
            #pragma unroll 2
            for (int p4 = 0; p4 < 32; ++p4) {
                const float x0 = xs[4 * p4 + 0][lane];
                const float x1 = xs[4 * p4 + 1][lane];
                const float x2 = xs[4 * p4 + 2][lane];
                const float x3 = xs[4 * p4 + 3][lane];
                #pragma unroll
                for (int r = 0; r < 8; ++r) {
                    const float4 w = h4[r * 32 + p4];
                    acc[r] = fmaf(w.w, x3, fmaf(w.z, x2, fmaf(w.y, x1, fmaf(w.x, x0, acc[r]))));
                }
            }
            ctxreg[gg * 2]     = (acc[0] > 0.f ? 1 : 0) | (acc[1] > 0.f ? 2 : 0) |
                                 (acc[2] > 0.f ? 4 : 0) | (acc[3] > 0.f ? 8 : 0);
            ctxreg[gg * 2 + 1] = (acc[4] > 0.f ? 1 : 0) | (acc[5] > 0.f ? 2 : 0) |
                                 (acc[6] > 0.f ? 4 : 0) | (acc[7] > 0.f ? 8 : 0);
        }
    }
    {
        const float4* h2 = reinterpret_cast<const float4*>(H2 + ((size_t)c * 4 + wid) * PP);
        float d = 0.f;
        #pragma unroll 8
        for (int p4 = 0; p4 < 32; ++p4) {
            const float4 w = h2[p4];
            d = fmaf(w.w, xs[4 * p4 + 3][lane], fmaf(w.z, xs[4 * p4 + 2][lane],
                fmaf(w.y, xs[4 * p4 + 1][lane], fmaf(w.x, xs[4 * p4 + 0][lane], d))));
        }
        bitss[wid][lane] = (d > 0.f) ? 1.f : 0.f;
        const float4* fw = reinterpret_cast<const float4*>(fc2w + (size_t)c * PP) + wid * 8;
        float ap = 0.f;
        #pragma unroll
        for (int p4 = 0; p4 < 8; ++p4) {
            const float4 w = fw[p4];
            const int p = wid * 32 + 4 * p4;
            ap = fmaf(w.w, xs[p + 3][lane], fmaf(w.z, xs[p + 2][lane],
                 fmaf(w.y, xs[p + 1][lane], fmaf(w.x, xs[p + 0][lane], ap))));
        }
        apart[wid][lane] = ap;
    }
    __syncthreads();

    float l1v[16];
    {
        const float4* W1c4 = reinterpret_cast<const float4*>(W1b) +
                             (size_t)(c * KK + wid * 16) * 512;
        #pragma unroll
        for (int gg = 0; gg < 2; ++gg) {
            float s[8] = {0.f, 0.f, 0.f, 0.f, 0.f, 0.f, 0.f, 0.f};
            const float4* wp[8];
            #pragma unroll
            for (int jj = 0; jj < 8; ++jj) {
                const int kk = gg * 8 + jj;
                wp[jj] = W1c4 + (size_t)kk * 512 + (size_t)ctxreg[kk] * 32;
            }
            #pragma unroll 2
            for (int p4 = 0; p4 < 32; ++p4) {
                const float x0 = fminf(fmaxf(xs[4 * p4 + 0][lane], -5.f), 5.f);
                const float x1 = fminf(fmaxf(xs[4 * p4 + 1][lane], -5.f), 5.f);
                const float x2 = fminf(fmaxf(xs[4 * p4 + 2][lane], -5.f), 5.f);
                const float x3 = fminf(fmaxf(xs[4 * p4 + 3][lane], -5.f), 5.f);
                #pragma unroll
                for (int jj = 0; jj < 8; ++jj) {
                    const float4 wv = wp[jj][p4];
                    s[jj] = fmaf(wv.w, x3, fmaf(wv.z, x2, fmaf(wv.y, x1, fmaf(wv.x, x0, s[jj]))));
                }
            }
            #pragma unroll
            for (int jj = 0; jj < 8; ++jj)
                l1v[gg * 8 + jj] = fminf(fmaxf(s[jj], -5.f), 5.f);
        }
    }
    {
        const int ctx2 = (bitss[0][lane] > 0.5f ? 1 : 0) | (bitss[1][lane] > 0.5f ? 2 : 0) |
                         (bitss[2][lane] > 0.5f ? 4 : 0) | (bitss[3][lane] > 0.5f ? 8 : 0);
        const float* w2 = W2 + ((size_t)c * NCTX_ + ctx2) * KK + wid * 16;
        float lp = 0.f;
        #pragma unroll
        for (int jj = 0; jj < 16; ++jj) lp = fmaf(w2[jj], l1v[jj], lp);
        l2part[wid][lane] = lp;
    }
    __syncthreads();
    if (wid == 0) {
        const int t = lane;
        const float l2 = (l2part[0][t] + l2part[1][t]) + (l2part[2][t] + l2part[3][t]);
        const float alpha = apart[0][t] + apart[1][t] + apart[2][t] + apart[3][t] + fc2b[c];
        const float bv = (1.f / (1.f + expf(-l2))) * (1.f / (1.f + expf(-alpha)));
        bout[(size_t)(tok0 + t) * CC + c] = bv;
    }
}

// ---------------------------------------------------------------------------
// Scan: b > 0 and relu-outputs >= 0 => relu is identity for t >= 1; along
// diagonal d the recurrence is a plain cumsum (bit-identical ordering).
// ---------------------------------------------------------------------------
__global__ __launch_bounds__(64) void scan_kernel(const float* __restrict__ hidden,
                                                  float* __restrict__ out)
{
    const int b    = blockIdx.x;
    const int lane = threadIdx.x;
    float* row = out + (size_t)b * SS * CC;
    const float hprev = hidden[b * CC + ((lane + 63) & 63)];

    float nb[64];
    #pragma unroll
    for (int j = 0; j < 64; ++j) nb[j] = row[j * CC + ((lane + j) & 63)];
    float acc = fmaxf(nb[0] + hprev, 0.f);
    row[lane] = acc;
    #pragma unroll
    for (int j = 1; j < 64; ++j) {
        acc += nb[j];
        row[j * CC + ((lane + j) & 63)] = acc;
    }
    for (int c0 = 64; c0 < SS; c0 += 64) {
        #pragma unroll
        for (int j = 0; j < 64; ++j)
            nb[j] = row[(c0 + j) * CC + ((lane + c0 + j) & 63)];
        #pragma unroll
        for (int j = 0; j < 64; ++j) {
            acc += nb[j];
            row[(c0 + j) * CC + ((lane + c0 + j) & 63)] = acc;
        }
    }
    out[(size_t)BB * SS * CC + b * CC + ((lane + 63) & 63)] = acc;
}

extern "C" void kernel_launch(void* const* d_in, const int* in_sizes, int n_in,
                              void* d_out, int out_size, void* d_ws, size_t ws_size,
                              hipStream_t stream) {
    const float* x      = (const float*)d_in[0];
    const float* hidden = (const float*)d_in[1];
    const float* H1     = (const float*)d_in[2];
    const float* W1     = (const float*)d_in[3];
    const float* H2     = (const float*)d_in[4];
    const float* W2     = (const float*)d_in[5];
    const float* fc2w   = (const float*)d_in[6];
    const float* fc2b   = (const float*)d_in[7];
    float* out = (float*)d_out;

    const size_t MB = 1024 * 1024;

    if (ws_size >= 24 * MB) {
        // layout: W1h[16MB] | H1h[4MB] | H1l[4MB]
        short* W1hp = (short*)d_ws;
        short* H1hp = (short*)((char*)d_ws + 16 * MB);
        short* H1lp = (short*)((char*)d_ws + 20 * MB);
        w1pack_kernel<<<dim3(CC * KK), 256, 0, stream>>>(W1, W1hp);
        h1pack_kernel<<<dim3(1024), 256, 0, stream>>>(H1, H1hp, H1lp);
        predict_kernel<<<dim3(CC * NTILES), 256, 0, stream>>>(
            x, H1hp, H1lp, W1hp, H2, W2, fc2w, fc2b, out);
    } else {
        predict_fb_kernel<<<dim3(CC * NTILES), 256, 0, stream>>>(
            x, H1, W1, H2, W2, fc2w, fc2b, out);
    }
    scan_kernel<<<dim3(BB), 64, 0, stream>>>(hidden, out);
}